// Round 1
// baseline (75.092 us; speedup 1.0000x reference)
//
#include <hip/hip_runtime.h>

// GravityMCDecoder: per-edge pairwise-distance decoder.
// d2(u,v) is symmetric, so one 64-dim squared distance per edge feeds both
// logits. The gather from z is the whole cost; z rows are 260 B (65 floats)
// so row bases are only 4B-aligned -> compiler emits scalar dword loads and
// every row spans ~5 cache lines. We repack into the (harness-poisoned,
// otherwise unused) workspace first:
//   rp[12288][64]  256B-aligned rows -> exactly 4 lines, dwordx4 loads
//   ma[12288]      compact 48 KB mass array -> L1-friendly m gathers
// Repack is 3 MB coalesced traffic (~2 us); edge kernel then runs in the
// aligned-gather regime with 4 edges per 16-lane group fully unrolled so
// ~16 wide loads are in flight per wave.

constexpr int kNodes = 12288;
constexpr int kD     = 64;    // D_PLUS_1 - 1
constexpr int kRow   = 65;    // row stride of z in floats
constexpr int kEdges = 262144;
constexpr float kEps = 0.01f;

// --- kernel 1: repack z -> rp (aligned 64f rows) + ma (compact masses) ----
// One float per thread, 12288*65 = 798720 threads, fully coalesced read.
__global__ __launch_bounds__(256) void repack_kernel(
    const float* __restrict__ z,
    float*       __restrict__ rp,
    float*       __restrict__ ma)
{
    const int f = blockIdx.x * 256 + threadIdx.x;   // < 798720, exact grid
    const int n = f / kRow;                          // magic-mul, no div
    const int d = f - n * kRow;
    const float val = z[f];
    if (d == kD) ma[n] = val;
    else         rp[(n << 6) + d] = val;
}

// --- kernel 2: 16 lanes per edge, 4 edges per group, fully unrolled ------
// Lane s covers dims [4s, 4s+3] via one aligned float4 load per row.
__global__ __launch_bounds__(256) void edge_kernel(
    const float* __restrict__ rp,
    const float* __restrict__ ma,
    const float* __restrict__ lptr,
    const int*   __restrict__ eidx,   // [2, kEdges] row-major: u's then v's
    float4*      __restrict__ out)    // [kEdges] = (p_nb, p_pu, p_pb, p_nu)
{
    const float l = lptr[0];
    const int tid = blockIdx.x * 256 + threadIdx.x;
    const int sub = tid & 15;                 // lane within edge group
    const int g   = tid >> 4;                 // edge group id, 0..65535
    constexpr int kStride = 65536;            // 4096 blocks * 256 / 16

    // Phase 1: all index loads in flight.
    int u[4], v[4];
#pragma unroll
    for (int i = 0; i < 4; ++i) {
        u[i] = eidx[g + i * kStride];
        v[i] = eidx[kEdges + g + i * kStride];
    }

    // Phase 2: all row fragments + masses in flight (8x dwordx4 + 8 bcast).
    float4 au[4], av[4];
    float  mu[4], mv[4];
#pragma unroll
    for (int i = 0; i < 4; ++i) {
        au[i] = *reinterpret_cast<const float4*>(rp + (u[i] << 6) + (sub << 2));
        av[i] = *reinterpret_cast<const float4*>(rp + (v[i] << 6) + (sub << 2));
        mu[i] = ma[u[i]];
        mv[i] = ma[v[i]];
    }

    // Phase 3: reduce + epilogue per edge.
#pragma unroll
    for (int i = 0; i < 4; ++i) {
        const float d0 = au[i].x - av[i].x;
        const float d1 = au[i].y - av[i].y;
        const float d2 = au[i].z - av[i].z;
        const float d3 = au[i].w - av[i].w;
        float p = d0 * d0;
        p = fmaf(d1, d1, p);
        p = fmaf(d2, d2, p);
        p = fmaf(d3, d3, p);
        // butterfly sum across the 16-lane group
        p += __shfl_xor(p, 1);
        p += __shfl_xor(p, 2);
        p += __shfl_xor(p, 4);
        p += __shfl_xor(p, 8);

        if (sub == 0) {
            const float logd     = __logf(p + kEps);
            const float logit_uv = mv[i] - l * logd;   // m[v] - l*log r2
            const float logit_vu = mu[i] - l * logd;   // m[u] - l*log r2
            const float suv = 1.f / (1.f + __expf(-logit_uv));
            const float svu = 1.f / (1.f + __expf(-logit_vu));
            out[g + i * kStride] = make_float4(
                (1.f - suv) * (1.f - svu),   // p_nb
                suv         * (1.f - svu),   // p_pu
                suv         * svu,           // p_pb
                (1.f - suv) * svu);          // p_nu
        }
    }
}

extern "C" void kernel_launch(void* const* d_in, const int* in_sizes, int n_in,
                              void* d_out, int out_size, void* d_ws, size_t ws_size,
                              hipStream_t stream) {
    const float* z    = (const float*)d_in[0];
    const float* lptr = (const float*)d_in[1];
    const int*   eidx = (const int*)d_in[2];
    float4*      out  = (float4*)d_out;

    float* rp = (float*)d_ws;                      // 12288*64 floats = 3.0 MB
    float* ma = (float*)d_ws + kNodes * kD;        // +48 KB, 256B-aligned off

    // 798720 floats / 256 = 3120 blocks, exact.
    repack_kernel<<<dim3((kNodes * kRow) / 256), dim3(256), 0, stream>>>(z, rp, ma);
    // 4096 blocks * 256 thr / 16 lanes = 65536 groups * 4 edges = 262144.
    edge_kernel<<<dim3(4096), dim3(256), 0, stream>>>(rp, ma, lptr, eidx, out);
}

// Round 2
// 71.043 us; speedup vs baseline: 1.0570x; 1.0570x over previous
//
#include <hip/hip_runtime.h>
#include <hip/hip_fp16.h>

// GravityMCDecoder: per-edge pairwise-distance decoder.
// Bottleneck is the random row gather (2 rows/edge, 262144 edges, ~42x node
// reuse but random order -> L2/LLC-cold after the harness's 268 MB poison).
// Attack the payload: repack coordinate rows to fp16 (128 B rows = exactly
// 2 cache lines, vs 5 lines for the raw 260 B fp32 rows). Precision: coords
// only feed a squared distance inside log(); fp16 rounding perturbs the
// output probabilities by ~5e-5, far below the 3.9e-3 current absmax.
//   rph[12288][64] half  (1.5 MB)  - one dwordx4 per 8-lane group per row
//   ma [12288]     float (48 KB)   - exact masses
// Edge kernel: 8 lanes/edge, 4 edges/thread batched for MLP, 2048 blocks
// = exactly 8 blocks/CU, single full-residency pass.

constexpr int kNodes = 12288;
constexpr int kD     = 64;    // D_PLUS_1 - 1
constexpr int kRow   = 65;    // row stride of z in floats
constexpr int kEdges = 262144;
constexpr float kEps = 0.01f;

// --- kernel 1: repack z -> rph (half rows) + ma (fp32 masses) -------------
// One float per thread, 12288*65 = 798720 threads, exact grid, coalesced.
__global__ __launch_bounds__(256) void repack_kernel(
    const float* __restrict__ z,
    __half*      __restrict__ rph,
    float*       __restrict__ ma)
{
    const int f = blockIdx.x * 256 + threadIdx.x;   // < 798720, exact grid
    const int n = f / kRow;                          // magic-mul, no div
    const int d = f - n * kRow;
    const float val = z[f];
    if (d == kD) ma[n] = val;
    else         rph[(n << 6) + d] = __float2half_rn(val);
}

union F4H {
    float4  f;
    __half2 h[4];
};

// --- kernel 2: 8 lanes/edge, 4 edges per thread, fully unrolled -----------
__global__ __launch_bounds__(256) void edge_kernel(
    const __half* __restrict__ rph,
    const float*  __restrict__ ma,
    const float*  __restrict__ lptr,
    const int*    __restrict__ eidx,   // [2, kEdges] row-major: u's then v's
    float4*       __restrict__ out)    // [kEdges] = (p_nb, p_pu, p_pb, p_nu)
{
    const float l = lptr[0];
    const int tid = blockIdx.x * 256 + threadIdx.x;
    const int sub = tid & 7;                  // lane within 8-lane edge group
    const int g   = tid >> 3;                 // edge group id, 0..65535
    constexpr int kStride = 65536;            // 2048 blocks * 256 / 8

    // Phase 1: all index loads in flight (each instr: 8 consecutive dwords
    // per wave -> 1 line).
    int u[4], v[4];
#pragma unroll
    for (int i = 0; i < 4; ++i) {
        u[i] = eidx[g + i * kStride];
        v[i] = eidx[kEdges + g + i * kStride];
    }

    // Phase 2: all row fragments + masses in flight.
    // Each row is 128 B = 2 lines; 8 lanes x 16 B contiguous.
    F4H  au[4], av[4];
    float mu[4], mv[4];
#pragma unroll
    for (int i = 0; i < 4; ++i) {
        au[i].f = *reinterpret_cast<const float4*>(rph + (u[i] << 6) + (sub << 3));
        av[i].f = *reinterpret_cast<const float4*>(rph + (v[i] << 6) + (sub << 3));
        mu[i] = ma[u[i]];
        mv[i] = ma[v[i]];
    }

    // Phase 3: reduce + epilogue per edge.
#pragma unroll
    for (int i = 0; i < 4; ++i) {
        float p = 0.f;
#pragma unroll
        for (int j = 0; j < 4; ++j) {
            const float2 fu = __half22float2(au[i].h[j]);
            const float2 fv = __half22float2(av[i].h[j]);
            const float dx = fu.x - fv.x;
            const float dy = fu.y - fv.y;
            p = fmaf(dx, dx, p);
            p = fmaf(dy, dy, p);
        }
        // butterfly sum across the 8-lane group (masks < 8 stay in-group)
        p += __shfl_xor(p, 1);
        p += __shfl_xor(p, 2);
        p += __shfl_xor(p, 4);

        if (sub == 0) {
            const float logd     = __logf(p + kEps);
            const float logit_uv = mv[i] - l * logd;   // m[v] - l*log r2
            const float logit_vu = mu[i] - l * logd;   // m[u] - l*log r2
            const float suv = 1.f / (1.f + __expf(-logit_uv));
            const float svu = 1.f / (1.f + __expf(-logit_vu));
            out[g + i * kStride] = make_float4(
                (1.f - suv) * (1.f - svu),   // p_nb
                suv         * (1.f - svu),   // p_pu
                suv         * svu,           // p_pb
                (1.f - suv) * svu);          // p_nu
        }
    }
}

extern "C" void kernel_launch(void* const* d_in, const int* in_sizes, int n_in,
                              void* d_out, int out_size, void* d_ws, size_t ws_size,
                              hipStream_t stream) {
    const float* z    = (const float*)d_in[0];
    const float* lptr = (const float*)d_in[1];
    const int*   eidx = (const int*)d_in[2];
    float4*      out  = (float4*)d_out;

    float*  ma  = (float*)d_ws;                        // 48 KB
    __half* rph = (__half*)((char*)d_ws + 64 * 1024);  // 1.5 MB, 64KB-aligned

    // 798720 floats / 256 = 3120 blocks, exact.
    repack_kernel<<<dim3((kNodes * kRow) / 256), dim3(256), 0, stream>>>(z, rph, ma);
    // 2048 blocks * 256 thr / 8 lanes = 65536 groups * 4 edges = 262144.
    edge_kernel<<<dim3(2048), dim3(256), 0, stream>>>(rph, ma, lptr, eidx, out);
}

// Round 3
// 71.017 us; speedup vs baseline: 1.0574x; 1.0004x over previous
//
#include <hip/hip_runtime.h>
#include <hip/hip_fp16.h>

// GravityMCDecoder: per-edge pairwise-distance decoder.
// Structure (established rounds 0-2):
//   repack z -> rph[12288][64] fp16 rows (128 B = 2 lines, dwordx4 gather)
//             + ma[12288] fp32 masses (48 KB, ~L1-resident)
//   edge kernel: 8 lanes/edge, 4 edges/group, one-shot full-residency pass.
// Round-3 deltas: (a) each group owns 4 CONSECUTIVE edges so the 8 scalar
// index loads collapse into 2 dwordx4 loads; (b) eidx loads are non-temporal
// (read-once 2 MB) so they don't evict the hot 1.5 MB rph set from L2.
// fp16 precision: coords feed a squared distance inside log(); measured
// absmax is pinned at 2^-8 by the reference's own cancellation, not us.

constexpr int kNodes = 12288;
constexpr int kD     = 64;    // D_PLUS_1 - 1
constexpr int kRow   = 65;    // row stride of z in floats
constexpr int kEdges = 262144;
constexpr float kEps = 0.01f;

typedef int   v4i __attribute__((ext_vector_type(4)));
typedef float v4f __attribute__((ext_vector_type(4)));

// --- kernel 1: repack z -> rph (half rows) + ma (fp32 masses) -------------
// One float per thread, 12288*65 = 798720 threads, exact grid, coalesced.
__global__ __launch_bounds__(256) void repack_kernel(
    const float* __restrict__ z,
    __half*      __restrict__ rph,
    float*       __restrict__ ma)
{
    const int f = blockIdx.x * 256 + threadIdx.x;   // < 798720, exact grid
    const int n = f / kRow;                          // magic-mul, no div
    const int d = f - n * kRow;
    const float val = z[f];
    if (d == kD) ma[n] = val;
    else         rph[(n << 6) + d] = __float2half_rn(val);
}

union F4H {
    float4  f;
    __half2 h[4];
};

// --- kernel 2: 8 lanes/edge, 4 consecutive edges per group ----------------
__global__ __launch_bounds__(256) void edge_kernel(
    const __half* __restrict__ rph,
    const float*  __restrict__ ma,
    const float*  __restrict__ lptr,
    const int*    __restrict__ eidx,   // [2, kEdges] row-major: u's then v's
    float4*       __restrict__ out)    // [kEdges] = (p_nb, p_pu, p_pb, p_nu)
{
    const float l = lptr[0];
    const int tid = blockIdx.x * 256 + threadIdx.x;
    const int sub = tid & 7;                  // lane within 8-lane edge group
    const int g   = tid >> 3;                 // group id, 0..65535

    // Phase 1: two vectorized index loads (edges 4g..4g+3), non-temporal.
    const v4i u4 = __builtin_nontemporal_load(
        reinterpret_cast<const v4i*>(eidx) + g);
    const v4i v4 = __builtin_nontemporal_load(
        reinterpret_cast<const v4i*>(eidx + kEdges) + g);
    const int u[4] = {u4.x, u4.y, u4.z, u4.w};
    const int v[4] = {v4.x, v4.y, v4.z, v4.w};

    // Phase 2: all row fragments + masses in flight.
    // Each row is 128 B = 2 lines; 8 lanes x 16 B contiguous per row.
    F4H  au[4], av[4];
    float mu[4], mv[4];
#pragma unroll
    for (int i = 0; i < 4; ++i) {
        au[i].f = *reinterpret_cast<const float4*>(rph + (u[i] << 6) + (sub << 3));
        av[i].f = *reinterpret_cast<const float4*>(rph + (v[i] << 6) + (sub << 3));
        mu[i] = ma[u[i]];
        mv[i] = ma[v[i]];
    }

    // Phase 3: reduce + epilogue per edge.
#pragma unroll
    for (int i = 0; i < 4; ++i) {
        float p = 0.f;
#pragma unroll
        for (int j = 0; j < 4; ++j) {
            const float2 fu = __half22float2(au[i].h[j]);
            const float2 fv = __half22float2(av[i].h[j]);
            const float dx = fu.x - fv.x;
            const float dy = fu.y - fv.y;
            p = fmaf(dx, dx, p);
            p = fmaf(dy, dy, p);
        }
        // butterfly sum across the 8-lane group (masks < 8 stay in-group)
        p += __shfl_xor(p, 1);
        p += __shfl_xor(p, 2);
        p += __shfl_xor(p, 4);

        if (sub == 0) {
            const float logd     = __logf(p + kEps);
            const float logit_uv = mv[i] - l * logd;   // m[v] - l*log r2
            const float logit_vu = mu[i] - l * logd;   // m[u] - l*log r2
            const float suv = 1.f / (1.f + __expf(-logit_uv));
            const float svu = 1.f / (1.f + __expf(-logit_vu));
            out[(g << 2) + i] = make_float4(
                (1.f - suv) * (1.f - svu),   // p_nb
                suv         * (1.f - svu),   // p_pu
                suv         * svu,           // p_pb
                (1.f - suv) * svu);          // p_nu
        }
    }
}

extern "C" void kernel_launch(void* const* d_in, const int* in_sizes, int n_in,
                              void* d_out, int out_size, void* d_ws, size_t ws_size,
                              hipStream_t stream) {
    const float* z    = (const float*)d_in[0];
    const float* lptr = (const float*)d_in[1];
    const int*   eidx = (const int*)d_in[2];
    float4*      out  = (float4*)d_out;

    float*  ma  = (float*)d_ws;                        // 48 KB
    __half* rph = (__half*)((char*)d_ws + 64 * 1024);  // 1.5 MB, 64KB-aligned

    // 798720 floats / 256 = 3120 blocks, exact.
    repack_kernel<<<dim3((kNodes * kRow) / 256), dim3(256), 0, stream>>>(z, rph, ma);
    // 2048 blocks * 256 thr / 8 lanes = 65536 groups * 4 edges = 262144.
    edge_kernel<<<dim3(2048), dim3(256), 0, stream>>>(rph, ma, lptr, eidx, out);
}